// Round 1
// baseline (2776.205 us; speedup 1.0000x reference)
//
#include <hip/hip_runtime.h>
#include <stdint.h>

#define EPS 1e-8f
#define NQ 16
#define DIM 1024
#define ROWS_PER_BLOCK 256
#define KT 32
#define NTHREADS 256

// Order-preserving bijection float -> uint32 (for max/argmax packing).
__device__ __forceinline__ unsigned int fkey(float f) {
    unsigned int b = __float_as_uint(f);
    return (b & 0x80000000u) ? ~b : (b | 0x80000000u);
}
__device__ __forceinline__ float funkey(unsigned int k) {
    unsigned int b = (k & 0x80000000u) ? (k & 0x7FFFFFFFu) : ~k;
    return __uint_as_float(b);
}

// Main kernel: each block processes a 256-row tile of the database.
// Thread t owns row (blockIdx.x*256 + t). K-loop tiled at KT=32 with a
// transposed LDS tile (pad 257 -> staging writes <=2-way, reads conflict-free).
// Query elements are read with wave-uniform indices -> s_load broadcast.
__global__ __launch_bounds__(NTHREADS, 4) void sim_kernel(
    const float* __restrict__ q,    // [16][1024]
    const float* __restrict__ db,   // [N][1024]
    int N,
    unsigned long long* __restrict__ pmax,  // [gridDim.x][16]
    float* __restrict__ psum)               // [gridDim.x][16]
{
    __shared__ float ldsT[KT][ROWS_PER_BLOCK + 1];
    __shared__ unsigned long long wk[4][NQ];
    __shared__ float wsum[4][NQ];

    const int tid = threadIdx.x;
    const int n0 = blockIdx.x * ROWS_PER_BLOCK;
    const long myrow = (long)n0 + tid;

    float dot[NQ];
#pragma unroll
    for (int i = 0; i < NQ; ++i) dot[i] = 0.f;
    float nsq = 0.f;

    const int r_ = tid >> 3;  // 0..31  (row within staging round)
    const int c_ = tid & 7;   // 0..7   (float4 column within k-tile)

    for (int kb = 0; kb < DIM; kb += KT) {
        __syncthreads();
        // Stage 256 rows x 32 cols, transposed into LDS. Coalesced 128B/row.
#pragma unroll
        for (int p = 0; p < 8; ++p) {
            const int rt = p * 32 + r_;               // row in tile 0..255
            long srow = (long)n0 + rt;
            if (srow >= N) srow = N - 1;              // clamp (masked later)
            const float4 v = *(const float4*)(db + srow * DIM + kb + c_ * 4);
            ldsT[c_ * 4 + 0][rt] = v.x;
            ldsT[c_ * 4 + 1][rt] = v.y;
            ldsT[c_ * 4 + 2][rt] = v.z;
            ldsT[c_ * 4 + 3][rt] = v.w;
        }
        __syncthreads();

        const float* qk = q + kb;  // uniform base
#pragma unroll
        for (int k = 0; k < KT; ++k) {
            const float d = ldsT[k][tid];
            nsq = fmaf(d, d, nsq);
#pragma unroll
            for (int qi = 0; qi < NQ; ++qi)
                dot[qi] = fmaf(qk[qi * DIM + k], d, dot[qi]);  // s_load operand
        }
    }

    // Per-row epilogue: scale by 1/(||d||+eps); q-norm divided out in finalize.
    const bool valid = (myrow < N);
    const float invd = 1.0f / (sqrtf(nsq) + EPS);

    unsigned long long pk[NQ];
    float sv[NQ];
#pragma unroll
    for (int qi = 0; qi < NQ; ++qi) {
        const float s = dot[qi] * invd;
        const unsigned int key = valid ? fkey(s) : 0u;
        pk[qi] = ((unsigned long long)key << 32) |
                 (unsigned long long)(0xFFFFFFFFu - (unsigned int)myrow);
        sv[qi] = valid ? s : 0.f;
    }

    // Wave (64-lane) shuffle reduction.
#pragma unroll
    for (int off = 32; off >= 1; off >>= 1) {
#pragma unroll
        for (int qi = 0; qi < NQ; ++qi) {
            const unsigned long long o = __shfl_down(pk[qi], off, 64);
            if (o > pk[qi]) pk[qi] = o;
            sv[qi] += __shfl_down(sv[qi], off, 64);
        }
    }

    const int wave = tid >> 6, lane = tid & 63;
    if (lane == 0) {
#pragma unroll
        for (int qi = 0; qi < NQ; ++qi) { wk[wave][qi] = pk[qi]; wsum[wave][qi] = sv[qi]; }
    }
    __syncthreads();
    if (tid < NQ) {
        unsigned long long best = wk[0][tid];
        float s = wsum[0][tid];
#pragma unroll
        for (int w = 1; w < 4; ++w) {
            if (wk[w][tid] > best) best = wk[w][tid];
            s += wsum[w][tid];
        }
        pmax[(long)blockIdx.x * NQ + tid] = best;
        psum[(long)blockIdx.x * NQ + tid] = s;
    }
}

// Finalize: q-norms, reduce per-block partials (deterministic), emit outputs.
__global__ __launch_bounds__(256) void finalize_kernel(
    const float* __restrict__ q,
    const int* __restrict__ db_classes,
    const int* __restrict__ y,
    const unsigned long long* __restrict__ pmax,
    const float* __restrict__ psum,
    int NB, int N,
    float* __restrict__ out)
{
    __shared__ float tmp[256];
    __shared__ float qn[NQ];
    __shared__ int mcls[NQ];
    __shared__ unsigned long long rmax[256];
    __shared__ float rsum[256];

    const int tid = threadIdx.x;

    // --- q norms: 16 threads/query, 64 elems each ---
    {
        const int qi = tid >> 4, c = tid & 15;
        float p = 0.f;
        for (int k = c * 64; k < c * 64 + 64; ++k) {
            const float v = q[qi * DIM + k];
            p = fmaf(v, v, p);
        }
        tmp[tid] = p;
        __syncthreads();
        for (int s = 8; s >= 1; s >>= 1) {
            if (c < s) tmp[tid] += tmp[tid + s];
            __syncthreads();
        }
        if (c == 0) qn[qi] = sqrtf(tmp[tid]) + EPS;
    }

    // --- reduce partials: thread t sticks to query t%16 (256 % 16 == 0) ---
    unsigned long long best = 0ull;
    float ssum = 0.f;
    const int total = NB * NQ;
    for (int e = tid; e < total; e += 256) {
        const unsigned long long v = pmax[e];
        if (v > best) best = v;
        ssum += psum[e];
    }
    rmax[tid] = best;
    rsum[tid] = ssum;
    __syncthreads();
    for (int s = 128; s >= 16; s >>= 1) {
        if (tid < s) {
            if (rmax[tid + s] > rmax[tid]) rmax[tid] = rmax[tid + s];
            rsum[tid] += rsum[tid + s];
        }
        __syncthreads();
    }

    if (tid < NQ) {
        const unsigned long long b = rmax[tid];
        const unsigned int ridx = 0xFFFFFFFFu - (unsigned int)(b & 0xFFFFFFFFull);
        const float sim_d = funkey((unsigned int)(b >> 32));  // dot/(||d||+eps)
        const float unit = sim_d / qn[tid];
        const float avg = rsum[tid] / qn[tid] / (float)N;
        const int cls = db_classes[ridx];
        out[tid] = unit;
        out[NQ + tid] = avg;
        out[2 * NQ + tid] = (float)cls;
        mcls[tid] = (cls == y[tid]) ? 1 : 0;
    }
    __syncthreads();
    if (tid == 0) {
        int cnt = 0;
#pragma unroll
        for (int i = 0; i < NQ; ++i) cnt += mcls[i];
        out[3 * NQ] = (float)cnt / (float)NQ;
    }
}

extern "C" void kernel_launch(void* const* d_in, const int* in_sizes, int n_in,
                              void* d_out, int out_size, void* d_ws, size_t ws_size,
                              hipStream_t stream) {
    const float* q = (const float*)d_in[0];
    const float* db = (const float*)d_in[1];
    const int* db_classes = (const int*)d_in[2];
    const int* y = (const int*)d_in[3];
    const int N = in_sizes[1] / DIM;  // 400000
    const int NB = (N + ROWS_PER_BLOCK - 1) / ROWS_PER_BLOCK;

    unsigned long long* pmax = (unsigned long long*)d_ws;
    float* psum = (float*)((char*)d_ws + (size_t)NB * NQ * sizeof(unsigned long long));

    sim_kernel<<<NB, NTHREADS, 0, stream>>>(q, db, N, pmax, psum);
    finalize_kernel<<<1, 256, 0, stream>>>(q, db_classes, y, pmax, psum, NB, N,
                                           (float*)d_out);
}